// Round 3
// baseline (212.308 us; speedup 1.0000x reference)
//
#include <hip/hip_runtime.h>
#include <hip/hip_bf16.h>
#include <stdint.h>

// out = x @ Wc^T + bc, where Wc = sum_k w_k * W[ids_k] (1024x1024), x:[4096][1024] fp32.
// prep: build Wc (bf16) + bc only (1024 blocks).
// gemm: 64(M)x128(N) tile, BK=64, 512 blocks (2/CU, 8 waves/CU), double-buffered LDS,
// single barrier per K-step, A reg-staged from fp32 with in-kernel bf16 convert,
// B staged via global_load_lds. XOR-swizzled LDS, MFMA 16x16x32 bf16.

typedef __attribute__((ext_vector_type(8))) short short8;
typedef __attribute__((ext_vector_type(8))) unsigned short ushort8;
typedef __attribute__((ext_vector_type(4))) float float4v;

#define DIMK 1024
#define DIMN 1024
#define DIMM 4096

__device__ __forceinline__ unsigned short f2bf_rtn(float f) {
  union { float f; unsigned u; } v; v.f = f;
  unsigned u = v.u;
  return (unsigned short)((u + 0x7fffu + ((u >> 16) & 1u)) >> 16);
}

// 1024 blocks: build Wc (bf16) + bc.
__global__ __launch_bounds__(256) void prep_kernel(
    const float* __restrict__ W, const float* __restrict__ bia,
    const int* __restrict__ ids, const float* __restrict__ wts,
    unsigned short* __restrict__ Wc, float* __restrict__ bc, int K)
{
  const int t  = blockIdx.x * 256 + threadIdx.x;   // float4 groups of Wc
  const int o  = t >> 8;
  const int d4 = (t & 255) << 2;
  float ax = 0.f, ay = 0.f, az = 0.f, aw = 0.f;
  for (int k = 0; k < K; ++k) {
    const float wk = wts[k];
    const float4 w4 = *reinterpret_cast<const float4*>(
        &W[((size_t)ids[k] << 20) + ((size_t)o << 10) + d4]);
    ax += wk * w4.x; ay += wk * w4.y; az += wk * w4.z; aw += wk * w4.w;
  }
  ushort4 r;
  r.x = f2bf_rtn(ax); r.y = f2bf_rtn(ay); r.z = f2bf_rtn(az); r.w = f2bf_rtn(aw);
  *reinterpret_cast<ushort4*>(&Wc[(size_t)t << 2]) = r;
  if (t < DIMN) {
    float s = 0.f;
    for (int k = 0; k < K; ++k) s += wts[k] * bia[ids[k] * DIMN + t];
    bc[t] = s;
  }
}

__device__ __forceinline__ void load_lds16(const void* g, void* l) {
  __builtin_amdgcn_global_load_lds(
      (const __attribute__((address_space(1))) void*)g,
      (__attribute__((address_space(3))) void*)l, 16, 0, 0);
}

// Tile 64(M) x 128(N), BK=64. 4 waves, wave computes 32x64 (2x4 MFMA 16x16x32).
// LDS layout XOR-swizzled: row r, global 16B-group g stored at phys group g^(r&7).
// B staging chunk = 8 rows x 64 cols (1 KB): global_load_lds writes lane l at
// base + l*16 -> row l>>3, phys group l&7, so lane's GLOBAL source column
// group = (l&7)^(l>>3).
// A staging: reg-staged fp32 -> bf16; thread t handles rows {t>>3, (t>>3)+32},
// group g=t&7, writes ushort8 at phys group g^(row&7) via ds_write_b128.
// ds_read: group g=s*4+quad at row r -> phys (s*4+quad)^(r16&7): conflict-free.
// K-loop: double-buffered, STAGE(next) before COMPUTE(cur), 1 barrier/K-step.
__global__ __launch_bounds__(256, 2) void gemm_kernel(
    const float* __restrict__ x,             // [4096][1024] fp32
    const unsigned short* __restrict__ Wc,   // [1024][1024] bf16 (row=n)
    const float* __restrict__ bc,            // [1024]
    float* __restrict__ out)                 // [4096][1024] fp32
{
  constexpr int BK = 64;
  __shared__ __align__(16) unsigned short As[2][64 * BK];    // 2 x 8 KB
  __shared__ __align__(16) unsigned short Bs[2][128 * BK];   // 2 x 16 KB

  const int tid  = threadIdx.x;
  const int wave = tid >> 6;
  const int lane = tid & 63;
  const int m0 = blockIdx.y * 64;
  const int n0 = blockIdx.x * 128;

  // --- B staging (global_load_lds): wave handles rows [wave*32, +32) as 4 chunks of 8 rows.
  const int srow = lane >> 3;
  const int scol = (((lane & 7) ^ srow) << 3);
  const unsigned short* gB = Wc + (size_t)(n0 + wave * 32 + srow) * DIMK + scol;

  // --- A staging (reg + cvt): thread t -> rows {arow, arow+32}, group ag.
  const int arow = tid >> 3;          // 0..31
  const int ag   = tid & 7;
  const int asw  = ((ag ^ (arow & 7)) << 3);   // phys col offset (same for arow+32)
  const float* gxa = x + (size_t)(m0 + arow) * DIMK + (ag << 3);
  float4 aR[4];

  const int wm   = (wave >> 1) * 32;
  const int wn   = (wave & 1) * 64;
  const int quad = lane >> 4;
  const int r16  = lane & 15;
  const int rx   = r16 & 7;
  const int po0  = ((quad ^ rx) << 3);        // kstep 0 phys group offset (elems)
  const int po1  = (((4 + quad) ^ rx) << 3);  // kstep 1

  const float4v zero = {0.f, 0.f, 0.f, 0.f};
  float4v acc[2][4];
#pragma unroll
  for (int i = 0; i < 2; ++i)
#pragma unroll
    for (int j = 0; j < 4; ++j) acc[i][j] = zero;

#define LOADA(kk)                                                              \
  do {                                                                         \
    const float* p = gxa + (size_t)(kk) * BK;                                  \
    aR[0] = *reinterpret_cast<const float4*>(p);                               \
    aR[1] = *reinterpret_cast<const float4*>(p + 4);                           \
    aR[2] = *reinterpret_cast<const float4*>(p + 32 * DIMK);                   \
    aR[3] = *reinterpret_cast<const float4*>(p + 32 * DIMK + 4);               \
  } while (0)

#define CVTWRITE(buf)                                                          \
  do {                                                                         \
    ushort8 w0, w1;                                                            \
    w0[0] = f2bf_rtn(aR[0].x); w0[1] = f2bf_rtn(aR[0].y);                      \
    w0[2] = f2bf_rtn(aR[0].z); w0[3] = f2bf_rtn(aR[0].w);                      \
    w0[4] = f2bf_rtn(aR[1].x); w0[5] = f2bf_rtn(aR[1].y);                      \
    w0[6] = f2bf_rtn(aR[1].z); w0[7] = f2bf_rtn(aR[1].w);                      \
    w1[0] = f2bf_rtn(aR[2].x); w1[1] = f2bf_rtn(aR[2].y);                      \
    w1[2] = f2bf_rtn(aR[2].z); w1[3] = f2bf_rtn(aR[2].w);                      \
    w1[4] = f2bf_rtn(aR[3].x); w1[5] = f2bf_rtn(aR[3].y);                      \
    w1[6] = f2bf_rtn(aR[3].z); w1[7] = f2bf_rtn(aR[3].w);                      \
    *reinterpret_cast<ushort8*>(&As[buf][arow * BK + asw]) = w0;               \
    *reinterpret_cast<ushort8*>(&As[buf][(arow + 32) * BK + asw]) = w1;        \
  } while (0)

#define STAGEB(buf, kstep)                                                     \
  do {                                                                         \
    _Pragma("unroll")                                                          \
    for (int c = 0; c < 4; ++c)                                                \
      load_lds16(gB + (size_t)(kstep) * BK + (size_t)c * 8 * DIMK,             \
                 &Bs[buf][(wave * 32 + c * 8) * BK]);                          \
  } while (0)

#define COMPUTE(buf)                                                           \
  do {                                                                         \
    _Pragma("unroll")                                                          \
    for (int s = 0; s < 2; ++s) {                                              \
      const int po = s ? po1 : po0;                                            \
      short8 af[2], bf[4];                                                     \
      _Pragma("unroll")                                                        \
      for (int mt = 0; mt < 2; ++mt)                                           \
        af[mt] = *reinterpret_cast<const short8*>(                             \
            &As[buf][(wm + mt * 16 + r16) * BK + po]);                         \
      _Pragma("unroll")                                                        \
      for (int nt = 0; nt < 4; ++nt)                                           \
        bf[nt] = *reinterpret_cast<const short8*>(                             \
            &Bs[buf][(wn + nt * 16 + r16) * BK + po]);                         \
      _Pragma("unroll")                                                        \
      for (int mt = 0; mt < 2; ++mt)                                           \
        _Pragma("unroll")                                                      \
        for (int nt = 0; nt < 4; ++nt)                                         \
          acc[mt][nt] = __builtin_amdgcn_mfma_f32_16x16x32_bf16(               \
              af[mt], bf[nt], acc[mt][nt], 0, 0, 0);                           \
    }                                                                          \
  } while (0)

  // prologue: stage K-step 0 into buffer 0
  LOADA(0);
  STAGEB(0, 0);
  CVTWRITE(0);
  __syncthreads();

  for (int t = 0; t < DIMK / BK; t += 2) {
    LOADA(t + 1);
    STAGEB(1, t + 1);
    COMPUTE(0);
    CVTWRITE(1);
    __syncthreads();
    if (t + 2 < DIMK / BK) { LOADA(t + 2); STAGEB(0, t + 2); }
    COMPUTE(1);
    if (t + 2 < DIMK / BK) CVTWRITE(0);
    __syncthreads();
  }

#undef LOADA
#undef CVTWRITE
#undef STAGEB
#undef COMPUTE

#pragma unroll
  for (int nt = 0; nt < 4; ++nt) {
    const int col = n0 + wn + nt * 16 + r16;
    const float bias = bc[col];
#pragma unroll
    for (int mt = 0; mt < 2; ++mt) {
      const int rbase = m0 + wm + mt * 16 + quad * 4;
#pragma unroll
      for (int r = 0; r < 4; ++r)
        out[(size_t)(rbase + r) * DIMN + col] = acc[mt][nt][r] + bias;
    }
  }
}

extern "C" void kernel_launch(void* const* d_in, const int* in_sizes, int n_in,
                              void* d_out, int out_size, void* d_ws, size_t ws_size,
                              hipStream_t stream) {
  const float* x   = (const float*)d_in[0];
  const float* W   = (const float*)d_in[1];
  const float* b   = (const float*)d_in[2];
  const int*   ids = (const int*)d_in[3];
  const float* wts = (const float*)d_in[4];
  float* out = (float*)d_out;
  const int K = in_sizes[3];

  // workspace: Wc 2 MB | bc 4 KB
  unsigned short* Wc = (unsigned short*)d_ws;
  float*          bc = (float*)((char*)d_ws + (2u << 20));

  prep_kernel<<<1024, 256, 0, stream>>>(W, b, ids, wts, Wc, bc, K);
  dim3 grid(DIMN / 128, DIMM / 64);   // 8 x 64 = 512 blocks, 2/CU
  gemm_kernel<<<grid, 256, 0, stream>>>(x, Wc, bc, out);
}

// Round 4
// 207.214 us; speedup vs baseline: 1.0246x; 1.0246x over previous
//
#include <hip/hip_runtime.h>
#include <hip/hip_bf16.h>
#include <stdint.h>

// out = x @ Wc^T + bc, where Wc = sum_k w_k * W[ids_k] (1024x1024), x:[4096][1024].
// prep: build Wc (bf16) + bc, convert x -> bf16 (8 floats/thread).
// gemm: 64(M)x128(N) tile, BK=64, 512 blocks (2/CU, 8 waves/CU), MFMA 16x16x32 bf16,
// double-buffered LDS (STAGE next before COMPUTE cur, 1 barrier/K-step),
// A and B both staged via global_load_lds into XOR-swizzled LDS.

typedef __attribute__((ext_vector_type(8))) short short8;
typedef __attribute__((ext_vector_type(4))) float float4v;

#define DIMK 1024
#define DIMN 1024
#define DIMM 4096

__device__ __forceinline__ unsigned short f2bf_rtn(float f) {
  union { float f; unsigned u; } v; v.f = f;
  unsigned u = v.u;
  return (unsigned short)((u + 0x7fffu + ((u >> 16) & 1u)) >> 16);
}

// blocks [0,1024): build Wc (bf16) + bc; blocks [1024,3072): convert x -> bf16 (8 floats/thread)
__global__ __launch_bounds__(256) void prep_kernel(
    const float* __restrict__ x, const float* __restrict__ W,
    const float* __restrict__ bia, const int* __restrict__ ids,
    const float* __restrict__ wts,
    unsigned short* __restrict__ xb, unsigned short* __restrict__ Wc,
    float* __restrict__ bc, int K)
{
  const int bid = blockIdx.x;
  if (bid < 1024) {
    const int t  = bid * 256 + threadIdx.x;   // float4 groups of Wc
    const int o  = t >> 8;
    const int d4 = (t & 255) << 2;
    float ax = 0.f, ay = 0.f, az = 0.f, aw = 0.f;
    for (int k = 0; k < K; ++k) {
      const float wk = wts[k];
      const float4 w4 = *reinterpret_cast<const float4*>(
          &W[((size_t)ids[k] << 20) + ((size_t)o << 10) + d4]);
      ax += wk * w4.x; ay += wk * w4.y; az += wk * w4.z; aw += wk * w4.w;
    }
    ushort4 r;
    r.x = f2bf_rtn(ax); r.y = f2bf_rtn(ay); r.z = f2bf_rtn(az); r.w = f2bf_rtn(aw);
    *reinterpret_cast<ushort4*>(&Wc[(size_t)t << 2]) = r;
    if (t < DIMN) {
      float s = 0.f;
      for (int k = 0; k < K; ++k) s += wts[k] * bia[ids[k] * DIMN + t];
      bc[t] = s;
    }
  } else {
    // 2048 blocks * 256 threads * 8 floats = 4096*1024
    const size_t t = (size_t)(bid - 1024) * 256 + threadIdx.x;
    const float4 v0 = *reinterpret_cast<const float4*>(&x[t << 3]);
    const float4 v1 = *reinterpret_cast<const float4*>(&x[(t << 3) + 4]);
    ushort4 r0, r1;
    r0.x = f2bf_rtn(v0.x); r0.y = f2bf_rtn(v0.y); r0.z = f2bf_rtn(v0.z); r0.w = f2bf_rtn(v0.w);
    r1.x = f2bf_rtn(v1.x); r1.y = f2bf_rtn(v1.y); r1.z = f2bf_rtn(v1.z); r1.w = f2bf_rtn(v1.w);
    *reinterpret_cast<ushort4*>(&xb[t << 3]) = r0;
    *reinterpret_cast<ushort4*>(&xb[(t << 3) + 4]) = r1;
  }
}

__device__ __forceinline__ void load_lds16(const void* g, void* l) {
  __builtin_amdgcn_global_load_lds(
      (const __attribute__((address_space(1))) void*)g,
      (__attribute__((address_space(3))) void*)l, 16, 0, 0);
}

// Tile 64(M) x 128(N), BK=64. 4 waves, wave computes 32x64 (2x4 MFMA 16x16x32).
// LDS layout XOR-swizzled: row r, global 16B-group g stored at phys group g^(r&7).
// Staging chunk = 8 rows x 64 cols (1 KB): global_load_lds writes lane l at
// base + l*16 -> row l>>3, phys group l&7, so lane's GLOBAL source column
// group = (l&7)^(l>>3)  (since row&7 == l>>3).
// ds_read: group g=s*4+quad at row r -> phys (s*4+quad)^(r16&7): conflict-free
// (8 distinct 4-bank groups x 2 lanes = 32 banks, 2-way = free).
// K-loop: double-buffered, STAGE(next) issued BEFORE COMPUTE(cur); the
// __syncthreads after COMPUTE provides the vmcnt(0)+barrier, so the prefetch
// has the whole MFMA phase to land. 1 barrier per K-step.
__global__ __launch_bounds__(256, 2) void gemm_kernel(
    const unsigned short* __restrict__ xb,   // [4096][1024] bf16
    const unsigned short* __restrict__ Wc,   // [1024][1024] bf16 (row=n)
    const float* __restrict__ bc,            // [1024]
    float* __restrict__ out)                 // [4096][1024] fp32
{
  constexpr int BK = 64;
  __shared__ __align__(16) unsigned short As[2][64 * BK];    // 2 x 8 KB
  __shared__ __align__(16) unsigned short Bs[2][128 * BK];   // 2 x 16 KB

  const int tid  = threadIdx.x;
  const int wave = tid >> 6;
  const int lane = tid & 63;
  const int m0 = blockIdx.y * 64;
  const int n0 = blockIdx.x * 128;

  // staging: wave handles A rows [wave*16, +16) as 2 chunks, B rows [wave*32, +32) as 4.
  const int srow = lane >> 3;
  const int scol = (((lane & 7) ^ srow) << 3);
  const unsigned short* gA0 = xb + (size_t)(m0 + wave * 16 + srow) * DIMK + scol;
  const unsigned short* gA1 = gA0 + 8 * DIMK;
  const unsigned short* gB0 = Wc + (size_t)(n0 + wave * 32 + srow) * DIMK + scol;
  const unsigned short* gB1 = gB0 + 8 * DIMK;
  const unsigned short* gB2 = gB0 + 16 * DIMK;
  const unsigned short* gB3 = gB0 + 24 * DIMK;
  const int lA0 = wave * 16 * BK;
  const int lA1 = lA0 + 8 * BK;
  const int lB0 = wave * 32 * BK;
  const int lB1 = lB0 + 8 * BK;
  const int lB2 = lB0 + 16 * BK;
  const int lB3 = lB0 + 24 * BK;

  const int wm   = (wave >> 1) * 32;
  const int wn   = (wave & 1) * 64;
  const int quad = lane >> 4;
  const int r16  = lane & 15;
  const int rx   = r16 & 7;
  const int po0  = ((quad ^ rx) << 3);        // kstep 0 phys group offset (elems)
  const int po1  = (((4 + quad) ^ rx) << 3);  // kstep 1

  const float4v zero = {0.f, 0.f, 0.f, 0.f};
  float4v acc[2][4];
#pragma unroll
  for (int i = 0; i < 2; ++i)
#pragma unroll
    for (int j = 0; j < 4; ++j) acc[i][j] = zero;

#define STAGE(buf, k0)                                                         \
  do {                                                                         \
    load_lds16(gA0 + (k0), &As[buf][lA0]);                                     \
    load_lds16(gA1 + (k0), &As[buf][lA1]);                                     \
    load_lds16(gB0 + (k0), &Bs[buf][lB0]);                                     \
    load_lds16(gB1 + (k0), &Bs[buf][lB1]);                                     \
    load_lds16(gB2 + (k0), &Bs[buf][lB2]);                                     \
    load_lds16(gB3 + (k0), &Bs[buf][lB3]);                                     \
  } while (0)

#define COMPUTE(buf)                                                           \
  do {                                                                         \
    _Pragma("unroll")                                                          \
    for (int s = 0; s < 2; ++s) {                                              \
      const int po = s ? po1 : po0;                                            \
      short8 af[2], bf[4];                                                     \
      _Pragma("unroll")                                                        \
      for (int mt = 0; mt < 2; ++mt)                                           \
        af[mt] = *reinterpret_cast<const short8*>(                             \
            &As[buf][(wm + mt * 16 + r16) * BK + po]);                         \
      _Pragma("unroll")                                                        \
      for (int nt = 0; nt < 4; ++nt)                                           \
        bf[nt] = *reinterpret_cast<const short8*>(                             \
            &Bs[buf][(wn + nt * 16 + r16) * BK + po]);                         \
      _Pragma("unroll")                                                        \
      for (int mt = 0; mt < 2; ++mt)                                           \
        _Pragma("unroll")                                                      \
        for (int nt = 0; nt < 4; ++nt)                                         \
          acc[mt][nt] = __builtin_amdgcn_mfma_f32_16x16x32_bf16(               \
              af[mt], bf[nt], acc[mt][nt], 0, 0, 0);                           \
    }                                                                          \
  } while (0)

  // prologue: stage K-step 0 into buffer 0
  STAGE(0, 0);
  __syncthreads();

  for (int t = 0; t < DIMK / BK; t += 2) {
    STAGE(1, (size_t)(t + 1) * BK);     // prefetch next while computing current
    COMPUTE(0);
    __syncthreads();
    if (t + 2 < DIMK / BK) STAGE(0, (size_t)(t + 2) * BK);
    COMPUTE(1);
    __syncthreads();
  }

#undef STAGE
#undef COMPUTE

#pragma unroll
  for (int nt = 0; nt < 4; ++nt) {
    const int col = n0 + wn + nt * 16 + r16;
    const float bias = bc[col];
#pragma unroll
    for (int mt = 0; mt < 2; ++mt) {
      const int rbase = m0 + wm + mt * 16 + quad * 4;
#pragma unroll
      for (int r = 0; r < 4; ++r)
        out[(size_t)(rbase + r) * DIMN + col] = acc[mt][nt][r] + bias;
    }
  }
}

extern "C" void kernel_launch(void* const* d_in, const int* in_sizes, int n_in,
                              void* d_out, int out_size, void* d_ws, size_t ws_size,
                              hipStream_t stream) {
  const float* x   = (const float*)d_in[0];
  const float* W   = (const float*)d_in[1];
  const float* b   = (const float*)d_in[2];
  const int*   ids = (const int*)d_in[3];
  const float* wts = (const float*)d_in[4];
  float* out = (float*)d_out;
  const int K = in_sizes[3];

  // workspace: xb 8 MB | Wc 2 MB | bc 4 KB
  unsigned short* xb = (unsigned short*)d_ws;
  unsigned short* Wc = (unsigned short*)((char*)d_ws + (8u << 20));
  float*          bc = (float*)((char*)d_ws + (10u << 20));

  prep_kernel<<<3072, 256, 0, stream>>>(x, W, b, ids, wts, xb, Wc, bc, K);
  dim3 grid(DIMN / 128, DIMM / 64);   // 8 x 64 = 512 blocks, 2/CU
  gemm_kernel<<<grid, 256, 0, stream>>>(xb, Wc, bc, out);
}